// Round 13
// baseline (442.963 us; speedup 1.0000x reference)
//
#include <hip/hip_runtime.h>
#include <hip/hip_bf16.h>

typedef unsigned long long u64;
typedef unsigned int u32;
typedef float fx2 __attribute__((ext_vector_type(2)));

#define IMG_H 256
#define IMG_W 256
#define CIN   64
#define HW    (IMG_H * IMG_W)   // 65536

// tile 32x16 = 512 px, 512 threads, 1 px/thread.
// bits1 window: 20x36 (tile +2 halo) ; bits2 frame: 18x34 (tile +1 halo)

// ---------------------------------------------------------------------------
// Kernel P: pack weight sign bits + per-out-channel alpha = mean(|w|).
// ---------------------------------------------------------------------------
__global__ void prep_kernel(const float* __restrict__ w1,
                            const float* __restrict__ w2,
                            u64* __restrict__ w1b, float* __restrict__ a1,
                            u64* __restrict__ w2b, float* __restrict__ a2) {
    int blk = blockIdx.x;
    int lane = threadIdx.x;  // 0..63
    const float* w;
    u64* wb;
    float* al;
    if (blk < 64) { w = w1 + (size_t)blk * 576;        wb = w1b + blk * 9;        al = a1 + blk; }
    else          { w = w2 + (size_t)(blk - 64) * 576; wb = w2b + (blk - 64) * 9; al = a2 + (blk - 64); }

    const float* wi = w + lane * 9;
    float s = 0.f;
    u64 bits[9];
#pragma unroll
    for (int t = 0; t < 9; ++t) {
        float v = wi[t];
        s += fabsf(v);
        bits[t] = __ballot(v > 0.f);
    }
#pragma unroll
    for (int m = 32; m >= 1; m >>= 1) s += __shfl_xor(s, m);
    if (lane == 0) {
        *al = s * (1.f / 576.f);
#pragma unroll
        for (int t = 0; t < 9; ++t) wb[t] = bits[t];
    }
}

// ---------------------------------------------------------------------------
// Fully fused: pack -> conv1 -> conv2 -> epilogue -> pixel_shuffle.
// Residual x / xres lives in 64 f32 REGISTERS per thread (never spilled:
// no occupancy bound, all indexing static via full unroll).
// ---------------------------------------------------------------------------
__global__ __launch_bounds__(512)
void fused_kernel(const float* __restrict__ x,
                  const float* __restrict__ b_in,
                  const float* __restrict__ b2_,
                  const u64* __restrict__ w1bits,
                  const float* __restrict__ alpha1,
                  const u64* __restrict__ w2bits,
                  const float* __restrict__ alpha2,
                  const float* __restrict__ b3,
                  const float* __restrict__ s2,
                  const float* __restrict__ b4,
                  float* __restrict__ out) {
    __shared__ u64 b1[20][36];   // bits1 window, origin (ty0-2, tx0-2)
    __shared__ u64 b2[18][34];   // bits2 frame,  origin (ty0-1, tx0-1)

    const int tid = threadIdx.x;           // 0..511
    const int n = blockIdx.z;
    const int tx0 = blockIdx.x * 32;
    const int ty0 = blockIdx.y * 16;
    const float* xn = x + (size_t)n * CIN * HW;

    const int py = tid >> 5;    // 0..15
    const int lx = tid & 31;    // 0..31
    const int gy = ty0 + py, gx = tx0 + lx;
    const int p = gy * IMG_W + gx;

    // ---- Phase A1: own pixel -> 64 f32 regs + own bits1 ----
    float rv[64];
    {
        u32 blo = 0, bhi = 0;
#pragma unroll
        for (int c = 0; c < 32; ++c) {
            float v = xn[(size_t)c * HW + p];
            rv[c] = v;
            blo |= (u32)((v + b_in[c]) > 0.f) << c;
        }
#pragma unroll
        for (int c = 0; c < 32; ++c) {
            float v = xn[(size_t)(c + 32) * HW + p];
            rv[c + 32] = v;
            bhi |= (u32)((v + b_in[c + 32]) > 0.f) << c;
        }
        b1[py + 2][lx + 2] = ((u64)bhi << 32) | blo;
    }

    // ---- Phase A2: bits1 for the 2-wide window ring (208 px) ----
    if (tid < 208) {
        int wy, wx;
        if (tid < 72)       { wy = tid / 36;            wx = tid % 36; }
        else if (tid < 144) { wy = 18 + (tid - 72) / 36; wx = (tid - 72) % 36; }
        else {
            int r = tid - 144;          // 0..63
            wy = 2 + (r >> 2);          // 2..17
            int c4 = r & 3;             // 0,1 -> cols 0,1 ; 2,3 -> cols 34,35
            wx = (c4 < 2) ? c4 : c4 + 32;
        }
        int ggy = ty0 + wy - 2, ggx = tx0 + wx - 2;
        u64 w = 0;
        if ((unsigned)ggy < (unsigned)IMG_H && (unsigned)ggx < (unsigned)IMG_W) {
            const float* pp = xn + ggy * IMG_W + ggx;
            u32 lo = 0, hi = 0;
#pragma unroll
            for (int c = 0; c < 32; ++c)
                lo |= (u32)((pp[(size_t)c * HW] + b_in[c]) > 0.f) << c;
#pragma unroll
            for (int c = 0; c < 32; ++c)
                hi |= (u32)((pp[(size_t)(c + 32) * HW] + b_in[c + 32]) > 0.f) << c;
            w = ((u64)hi << 32) | lo;
        }
        b1[wy][wx] = w;
    }
    __syncthreads();

    // validity mask for own px (identical for conv1 and conv2: 3x3 SAME)
    int invm = 0, nv = 0;
#pragma unroll
    for (int t = 0; t < 9; ++t) {
        int dy = t / 3 - 1, dx = t % 3 - 1;
        bool v = ((unsigned)(gy + dy) < (unsigned)IMG_H) &
                 ((unsigned)(gx + dx) < (unsigned)IMG_W);
        invm |= (v ? 0 : 1) << t;
        nv += v ? 1 : 0;
    }

    // ---- Phase B1: conv1 own px; rv becomes xres (f32); own bits2 ----
    {
        u64 W1[9];
#pragma unroll
        for (int t = 0; t < 9; ++t)
            W1[t] = b1[py + 1 + t / 3][lx + 1 + t % 3];

        u64 w2own = 0;
#pragma unroll
        for (int g = 0; g < 8; ++g) {
            u32 gm = 0;
#pragma unroll
            for (int j = 0; j < 8; ++j) {
                int o = g * 8 + j;
                const u64* wo = w1bits + o * 9;
                int D = 0;
#pragma unroll
                for (int t = 0; t < 9; ++t) D += __popcll(W1[t] ^ wo[t]);
                int S = 64 * nv - 2 * D;
                if (invm) {
#pragma unroll
                    for (int t = 0; t < 9; ++t)
                        if ((invm >> t) & 1) S += 2 * __popcll(wo[t]);
                }
                float r = alpha1[o] * (float)S + rv[o];
                rv[o] = r;
                gm |= (u32)((r + b2_[o]) > 0.f) << j;
            }
            w2own |= (u64)gm << (8 * g);
        }
        b2[py + 1][lx + 1] = w2own;
    }

    // ---- Phase B2: bits2 for the 1-wide frame ring (100 px) ----
    if (tid < 100) {
        int fy, fx;
        if (tid < 34)      { fy = 0;  fx = tid; }
        else if (tid < 68) { fy = 17; fx = tid - 34; }
        else { int r = tid - 68; fy = 1 + (r >> 1); fx = (r & 1) ? 33 : 0; }
        int ggy = ty0 + fy - 1, ggx = tx0 + fx - 1;
        u64 w2w = 0;
        if ((unsigned)ggy < (unsigned)IMG_H && (unsigned)ggx < (unsigned)IMG_W) {
            u64 xb[9];
            int im = 0, nvv = 0;
#pragma unroll
            for (int t = 0; t < 9; ++t) {
                int dy = t / 3 - 1, dx = t % 3 - 1;
                bool v = ((unsigned)(ggy + dy) < (unsigned)IMG_H) &
                         ((unsigned)(ggx + dx) < (unsigned)IMG_W);
                xb[t] = b1[fy + t / 3][fx + t % 3];
                im |= (v ? 0 : 1) << t;
                nvv += v ? 1 : 0;
            }
            const float* pp = xn + ggy * IMG_W + ggx;
#pragma unroll
            for (int g = 0; g < 8; ++g) {
                u32 gm = 0;
#pragma unroll
                for (int j = 0; j < 8; ++j) {
                    int o = g * 8 + j;
                    const u64* wo = w1bits + o * 9;
                    int D = 0;
#pragma unroll
                    for (int t = 0; t < 9; ++t) D += __popcll(xb[t] ^ wo[t]);
                    int S = 64 * nvv - 2 * D;
                    if (im) {
#pragma unroll
                        for (int t = 0; t < 9; ++t)
                            if ((im >> t) & 1) S += 2 * __popcll(wo[t]);
                    }
                    float r = alpha1[o] * (float)S + pp[(size_t)o * HW];
                    gm |= (u32)((r + b2_[o]) > 0.f) << j;
                }
                w2w |= (u64)gm << (8 * g);
            }
        }
        b2[fy][fx] = w2w;
    }
    __syncthreads();

    // ---- Phase C: conv2 + shortcut + b3 + PReLU + b4 + pixel shuffle ----
    u64 W2[9];
#pragma unroll
    for (int t = 0; t < 9; ++t)
        W2[t] = b2[py + t / 3][lx + t % 3];

    float* ob = out + (size_t)n * 32 * 512 * 512;
    const int Y = 2 * gy, X = 2 * gx;

#pragma unroll
    for (int g = 0; g < 8; ++g) {
#pragma unroll
        for (int jj = 0; jj < 8; jj += 2) {
            float vlo[2], vhi[2];
#pragma unroll
            for (int q = 0; q < 2; ++q) {
                int o = g * 8 + jj + q;
                float xrv = rv[o];
                // low channel o
                {
                    const u64* wo = w2bits + o * 9;
                    int D = 0;
#pragma unroll
                    for (int t = 0; t < 9; ++t) D += __popcll(W2[t] ^ wo[t]);
                    int S = 64 * nv - 2 * D;
                    if (invm) {
#pragma unroll
                        for (int t = 0; t < 9; ++t)
                            if ((invm >> t) & 1) S += 2 * __popcll(wo[t]);
                    }
                    float u = 1.25f * alpha2[o] * (float)S + xrv + b3[o];
                    u = (u >= 0.f) ? u : s2[o] * u;
                    vlo[q] = u + b4[o];
                }
                // high channel o + 64
                {
                    int o2 = o + 64;
                    const u64* wo = w2bits + o2 * 9;
                    int D = 0;
#pragma unroll
                    for (int t = 0; t < 9; ++t) D += __popcll(W2[t] ^ wo[t]);
                    int S = 64 * nv - 2 * D;
                    if (invm) {
#pragma unroll
                        for (int t = 0; t < 9; ++t)
                            if ((invm >> t) & 1) S += 2 * __popcll(wo[t]);
                    }
                    float u = 1.25f * alpha2[o2] * (float)S + xrv + b3[o2];
                    u = (u >= 0.f) ? u : s2[o2] * u;
                    vhi[q] = u + b4[o2];
                }
            }
            // o = co*4 + r1*2 + r2; (o,o+1) -> cols X, X+1 of row (co, Y+r1)
            int o = g * 8 + jj;
            int co = o >> 2;
            int r1 = (o >> 1) & 1;
            fx2 vl; vl.x = vlo[0]; vl.y = vlo[1];
            fx2 vh; vh.x = vhi[0]; vh.y = vhi[1];
            __builtin_nontemporal_store(
                vl, (fx2*)(ob + ((size_t)co * 512 + Y + r1) * 512 + X));
            __builtin_nontemporal_store(
                vh, (fx2*)(ob + ((size_t)(co + 16) * 512 + Y + r1) * 512 + X));
        }
    }
}

// ---------------------------------------------------------------------------
extern "C" void kernel_launch(void* const* d_in, const int* in_sizes, int n_in,
                              void* d_out, int out_size, void* d_ws, size_t ws_size,
                              hipStream_t stream) {
    const float* x    = (const float*)d_in[0];
    const float* w1   = (const float*)d_in[1];
    const float* w2   = (const float*)d_in[2];
    const float* b_in = (const float*)d_in[3];
    // d_in[4]=b1, d_in[5]=s1, d_in[6]=b2 are dead code in the reference
    const float* b2_  = (const float*)d_in[7];
    const float* b3   = (const float*)d_in[8];
    const float* s2   = (const float*)d_in[9];
    const float* b4   = (const float*)d_in[10];
    float* out = (float*)d_out;

    char* ws = (char*)d_ws;
    u64*   w1b = (u64*)(ws + 0);        // 4608 B
    u64*   w2b = (u64*)(ws + 4608);     // 9216 B
    float* a1  = (float*)(ws + 13824);  // 256 B
    float* a2  = (float*)(ws + 14080);  // 512 B

    prep_kernel<<<192, 64, 0, stream>>>(w1, w2, w1b, a1, w2b, a2);

    dim3 grid(IMG_W / 32, IMG_H / 16, 8);   // 8 x 16 x 8 = 1024 blocks
    fused_kernel<<<grid, 512, 0, stream>>>(x, b_in, b2_, w1b, a1, w2b, a2,
                                           b3, s2, b4, out);
}

// Round 14
// 204.382 us; speedup vs baseline: 2.1673x; 2.1673x over previous
//
#include <hip/hip_runtime.h>
#include <hip/hip_bf16.h>

typedef unsigned long long u64;
typedef unsigned int u32;
typedef unsigned short ushort8 __attribute__((ext_vector_type(8)));
typedef unsigned short ushortx16 __attribute__((ext_vector_type(16)));
typedef u64 u64x2 __attribute__((ext_vector_type(2)));
typedef u64 u64x4 __attribute__((ext_vector_type(4)));
typedef float fx2 __attribute__((ext_vector_type(2)));
typedef float fx4 __attribute__((ext_vector_type(4)));

#define IMG_H 256
#define IMG_W 256
#define CIN   64
#define HW    (IMG_H * IMG_W)   // 65536
#define NPIX  (8 * HW)          // 524288

static __device__ __forceinline__ float bf16bits_to_f32(unsigned short h) {
    union { u32 u; float f; } c;
    c.u = ((u32)h) << 16;
    return c.f;
}
static __device__ __forceinline__ unsigned short f32_to_bf16bits(float f) {
    __hip_bfloat16 hb = __float2bfloat16(f);
    return *(unsigned short*)&hb;
}

// ---------------------------------------------------------------------------
// Kernel P: pack weight sign bits + per-out-channel alpha = mean(|w|).
// ---------------------------------------------------------------------------
__global__ void prep_kernel(const float* __restrict__ w1,
                            const float* __restrict__ w2,
                            u64* __restrict__ w1b, float* __restrict__ a1,
                            u64* __restrict__ w2b, float* __restrict__ a2) {
    int blk = blockIdx.x;
    int lane = threadIdx.x;  // 0..63
    const float* w;
    u64* wb;
    float* al;
    if (blk < 64) { w = w1 + (size_t)blk * 576;        wb = w1b + blk * 9;        al = a1 + blk; }
    else          { w = w2 + (size_t)(blk - 64) * 576; wb = w2b + (blk - 64) * 9; al = a2 + (blk - 64); }

    const float* wi = w + lane * 9;
    float s = 0.f;
    u64 bits[9];
#pragma unroll
    for (int t = 0; t < 9; ++t) {
        float v = wi[t];
        s += fabsf(v);
        bits[t] = __ballot(v > 0.f);
    }
#pragma unroll
    for (int m = 32; m >= 1; m >>= 1) s += __shfl_xor(s, m);
    if (lane == 0) {
        *al = s * (1.f / 576.f);
#pragma unroll
        for (int t = 0; t < 9; ++t) wb[t] = bits[t];
    }
}

// ---------------------------------------------------------------------------
// Kernel 1: pack sign(x + b_in). 4 px/thread, fx4 loads, u32 bit accum.
// ---------------------------------------------------------------------------
__global__ __launch_bounds__(256)
void pack_kernel(const float* __restrict__ x,
                 const float* __restrict__ b_in,
                 u64* __restrict__ bits1) {
    int tid = blockIdx.x * 256 + threadIdx.x;     // over NPIX/4
    int n = tid >> 14;
    int p = (tid & 16383) * 4;
    const float* xp = x + (size_t)n * CIN * HW + p;
    u32 lo[4] = {0, 0, 0, 0}, hi[4] = {0, 0, 0, 0};
#pragma unroll
    for (int c = 0; c < 32; ++c) {
        fx4 v = *(const fx4*)(xp + (size_t)c * HW);
        float b = b_in[c];
#pragma unroll
        for (int q = 0; q < 4; ++q) lo[q] |= (u32)((v[q] + b) > 0.f) << c;
    }
#pragma unroll
    for (int c = 0; c < 32; ++c) {
        fx4 v = *(const fx4*)(xp + (size_t)(c + 32) * HW);
        float b = b_in[c + 32];
#pragma unroll
        for (int q = 0; q < 4; ++q) hi[q] |= (u32)((v[q] + b) > 0.f) << c;
    }
    u64x4 pk;
#pragma unroll
    for (int q = 0; q < 4; ++q) pk[q] = ((u64)hi[q] << 32) | lo[q];
    *(u64x4*)(bits1 + (size_t)n * HW + p) = pk;
}

// ---------------------------------------------------------------------------
// Kernel 2: conv1 (binary popcount from bits1) + residual. 1 px/thread,
// A/B software pipeline (r8 structure). xres/bits2 written NON-TEMPORAL:
// single-use intermediates, keep them out of L2.
// ---------------------------------------------------------------------------
__global__ __launch_bounds__(256)
void conv1_kernel(const float* __restrict__ x,
                  const float* __restrict__ b2_,
                  const u64* __restrict__ bits1,
                  const u64* __restrict__ wbits,
                  const float* __restrict__ alpha1,
                  ushort8* __restrict__ xres,
                  u64* __restrict__ bits2) {
    int i = blockIdx.x * 256 + threadIdx.x;
    int n = i >> 16, p = i & 65535;
    int y = p >> 8, xc = p & 255;

    u64 xb[9];
    int invmask = 0, nv = 0;
#pragma unroll
    for (int t = 0; t < 9; ++t) {
        int dy = t / 3 - 1, dx = t % 3 - 1;
        bool v = ((unsigned)(y + dy) < (unsigned)IMG_H) &
                 ((unsigned)(xc + dx) < (unsigned)IMG_W);
        xb[t] = v ? bits1[i + dy * IMG_W + dx] : 0ull;
        invmask |= (v ? 0 : 1) << t;
        nv += v ? 1 : 0;
    }

    const float* xp = x + (size_t)n * CIN * HW + p;
    u64 w2 = 0;

    float rvA[8], rvB[8];

    auto load_rv = [&](float* buf, int g) {
#pragma unroll
        for (int j = 0; j < 8; ++j)
            buf[j] = xp[(size_t)(g * 8 + j) * HW];
    };
    auto comp = [&](const float* buf, int g) {
        ushort8 pk;
        u32 gm = 0;
#pragma unroll
        for (int j = 0; j < 8; ++j) {
            int o = g * 8 + j;
            const u64* wo = wbits + o * 9;
            int D = 0;
#pragma unroll
            for (int t = 0; t < 9; ++t) D += __popcll(xb[t] ^ wo[t]);
            int S = 64 * nv - 2 * D;
            if (invmask) {
#pragma unroll
                for (int t = 0; t < 9; ++t)
                    if ((invmask >> t) & 1) S += 2 * __popcll(wo[t]);
            }
            float r = alpha1[o] * (float)S + buf[j];
            pk[j] = f32_to_bf16bits(r);
            gm |= (u32)((r + b2_[o]) > 0.f) << j;
        }
        __builtin_nontemporal_store(pk, xres + (size_t)(n * 8 + g) * HW + p);
        w2 |= (u64)gm << (8 * g);
    };

    load_rv(rvA, 0);
#pragma unroll 1
    for (int gg = 0; gg < 4; ++gg) {
        load_rv(rvB, 2 * gg + 1);
        comp(rvA, 2 * gg);
        if (gg < 3) load_rv(rvA, 2 * gg + 2);
        comp(rvB, 2 * gg + 1);
    }
    __builtin_nontemporal_store(w2, bits2 + i);
}

// ---------------------------------------------------------------------------
// Kernel 3: conv2 + shortcut + b3 + PReLU(s2) + b4 + fused pixel_shuffle(2).
// 2 px/thread, fx4 NT stores, A/B pipelined xres loads (r8 structure).
// xres loads NON-TEMPORAL: single-use, keep L2 for bits2 taps.
// ---------------------------------------------------------------------------
__global__ __launch_bounds__(256)
void conv2_kernel(const ushort8* __restrict__ xres,
                  const u64* __restrict__ bits2,
                  const u64* __restrict__ wbits,
                  const float* __restrict__ alpha2,
                  const float* __restrict__ b3,
                  const float* __restrict__ s2,
                  const float* __restrict__ b4,
                  float* __restrict__ out) {
    int tid = blockIdx.x * 256 + threadIdx.x;   // over NPIX/2
    int n = tid >> 15;
    int p = (tid & 32767) * 2;
    int y = p >> 8, xc = p & 255;   // xc even

    u64 W[3][4];
    const u64* bp = bits2 + (size_t)n * HW;
#pragma unroll
    for (int r = 0; r < 3; ++r) {
        int yy = y - 1 + r;
        bool rv = (unsigned)yy < (unsigned)IMG_H;
        const u64* row = bp + yy * IMG_W + xc;
        W[r][0] = (rv && xc > 0)   ? row[-1] : 0ull;
        W[r][1] = rv ? row[0] : 0ull;
        W[r][2] = rv ? row[1] : 0ull;
        W[r][3] = (rv && xc < 254) ? row[2]  : 0ull;
    }
    int inv0 = 0, inv1 = 0, nv0 = 0, nv1 = 0;
#pragma unroll
    for (int t = 0; t < 9; ++t) {
        const int r = t / 3, c = t % 3;
        bool rv = (unsigned)(y - 1 + r) < (unsigned)IMG_H;
        bool v0 = rv && !(c == 0 && xc == 0);
        bool v1 = rv && !(c == 2 && xc == 254);
        inv0 |= (v0 ? 0 : 1) << t; nv0 += v0 ? 1 : 0;
        inv1 |= (v1 ? 0 : 1) << t; nv1 += v1 ? 1 : 0;
    }
    const int edge = inv0 | inv1;

    const ushortx16* xrp = (const ushortx16*)(xres + (size_t)n * 8 * HW + p);
    float* ob = out + (size_t)n * 32 * 512 * 512;
    const int Y = 2 * y, X = 2 * xc;

    ushortx16 xrA, xrB;

    auto comp = [&](const ushortx16& xr, int g) {
#pragma unroll
        for (int jj = 0; jj < 8; jj += 2) {
            float lo4[4], hi4[4];
#pragma unroll
            for (int q = 0; q < 2; ++q) {
                int o = g * 8 + jj + q;
                float xrv0 = bf16bits_to_f32(xr[jj + q]);       // px0
                float xrv1 = bf16bits_to_f32(xr[8 + jj + q]);   // px1
                // low channel o
                {
                    const u64* wo = wbits + o * 9;
                    int D0 = 0, D1 = 0;
#pragma unroll
                    for (int t = 0; t < 9; ++t) {
                        const int r = t / 3, c = t % 3;
                        u64 w = wo[t];
                        D0 += __popcll(W[r][c] ^ w);
                        D1 += __popcll(W[r][c + 1] ^ w);
                    }
                    int S0 = 64 * nv0 - 2 * D0;
                    int S1 = 64 * nv1 - 2 * D1;
                    if (edge) {
#pragma unroll
                        for (int t = 0; t < 9; ++t) {
                            int pw = __popcll(wo[t]);
                            if ((inv0 >> t) & 1) S0 += 2 * pw;
                            if ((inv1 >> t) & 1) S1 += 2 * pw;
                        }
                    }
                    float ka = 1.25f * alpha2[o], bb = b3[o], ss = s2[o], b4v = b4[o];
                    float u0 = ka * (float)S0 + xrv0 + bb;
                    float u1 = ka * (float)S1 + xrv1 + bb;
                    u0 = (u0 >= 0.f) ? u0 : ss * u0;
                    u1 = (u1 >= 0.f) ? u1 : ss * u1;
                    lo4[q] = u0 + b4v;
                    lo4[2 + q] = u1 + b4v;
                }
                // high channel o + 64
                {
                    int o2 = o + 64;
                    const u64* wo = wbits + o2 * 9;
                    int D0 = 0, D1 = 0;
#pragma unroll
                    for (int t = 0; t < 9; ++t) {
                        const int r = t / 3, c = t % 3;
                        u64 w = wo[t];
                        D0 += __popcll(W[r][c] ^ w);
                        D1 += __popcll(W[r][c + 1] ^ w);
                    }
                    int S0 = 64 * nv0 - 2 * D0;
                    int S1 = 64 * nv1 - 2 * D1;
                    if (edge) {
#pragma unroll
                        for (int t = 0; t < 9; ++t) {
                            int pw = __popcll(wo[t]);
                            if ((inv0 >> t) & 1) S0 += 2 * pw;
                            if ((inv1 >> t) & 1) S1 += 2 * pw;
                        }
                    }
                    float ka = 1.25f * alpha2[o2], bb = b3[o2], ss = s2[o2], b4v = b4[o2];
                    float u0 = ka * (float)S0 + xrv0 + bb;
                    float u1 = ka * (float)S1 + xrv1 + bb;
                    u0 = (u0 >= 0.f) ? u0 : ss * u0;
                    u1 = (u1 >= 0.f) ? u1 : ss * u1;
                    hi4[q] = u0 + b4v;
                    hi4[2 + q] = u1 + b4v;
                }
            }
            // o = co*4 + r1*2 + r2: (o,o+1) at px0 -> cols X,X+1; px1 -> X+2,X+3
            int o = g * 8 + jj;
            int co = o >> 2;
            int r1 = (o >> 1) & 1;
            fx4 vl; vl.x = lo4[0]; vl.y = lo4[1]; vl.z = lo4[2]; vl.w = lo4[3];
            fx4 vh; vh.x = hi4[0]; vh.y = hi4[1]; vh.z = hi4[2]; vh.w = hi4[3];
            __builtin_nontemporal_store(
                vl, (fx4*)(ob + ((size_t)co * 512 + Y + r1) * 512 + X));
            __builtin_nontemporal_store(
                vh, (fx4*)(ob + ((size_t)(co + 16) * 512 + Y + r1) * 512 + X));
        }
    };

    xrA = __builtin_nontemporal_load(xrp);
#pragma unroll 1
    for (int gg = 0; gg < 4; ++gg) {
        xrB = __builtin_nontemporal_load(xrp + (size_t)(2 * gg + 1) * (HW / 2));
        comp(xrA, 2 * gg);
        if (gg < 3) xrA = __builtin_nontemporal_load(xrp + (size_t)(2 * gg + 2) * (HW / 2));
        comp(xrB, 2 * gg + 1);
    }
}

// ---------------------------------------------------------------------------
extern "C" void kernel_launch(void* const* d_in, const int* in_sizes, int n_in,
                              void* d_out, int out_size, void* d_ws, size_t ws_size,
                              hipStream_t stream) {
    const float* x    = (const float*)d_in[0];
    const float* w1   = (const float*)d_in[1];
    const float* w2   = (const float*)d_in[2];
    const float* b_in = (const float*)d_in[3];
    // d_in[4]=b1, d_in[5]=s1, d_in[6]=b2 are dead code in the reference
    const float* b2_  = (const float*)d_in[7];
    const float* b3   = (const float*)d_in[8];
    const float* s2   = (const float*)d_in[9];
    const float* b4   = (const float*)d_in[10];
    float* out = (float*)d_out;

    char* ws = (char*)d_ws;
    u64*   w1b   = (u64*)(ws + 0);                    // 4608 B
    u64*   w2b   = (u64*)(ws + 4608);                 // 9216 B
    float* a1    = (float*)(ws + 13824);              // 256 B
    float* a2    = (float*)(ws + 14080);              // 512 B
    u64*   bits1 = (u64*)(ws + 16384);                // 4 MiB
    u64*   bits2 = (u64*)(ws + 16384 + 4194304);      // 4 MiB
    ushort8* xres = (ushort8*)(ws + 16384 + 2 * 4194304);  // 64 MiB

    prep_kernel<<<192, 64, 0, stream>>>(w1, w2, w1b, a1, w2b, a2);

    pack_kernel <<<NPIX / 1024, 256, 0, stream>>>(x, b_in, bits1);
    conv1_kernel<<<NPIX / 256, 256, 0, stream>>>(x, b2_, bits1, w1b, a1, xres, bits2);
    conv2_kernel<<<NPIX / 512, 256, 0, stream>>>(xres, bits2, w2b, a2, b3, s2, b4, out);
}